// Round 3
// baseline (10555.584 us; speedup 1.0000x reference)
//
#include <hip/hip_runtime.h>

#define Bdim 64
#define Tdim 512
#define Idim 512
#define Hdim 512
#define CLIPV 10.0f
#define CPW 64      // columns per WG (column-split factor 8)

typedef __attribute__((ext_vector_type(4))) float f32x4;
typedef __attribute__((ext_vector_type(8))) short bf16x8;

__device__ __forceinline__ ushort f2bf(float f) {
    unsigned u = __builtin_bit_cast(unsigned, f);
    u += 0x7fffu + ((u >> 16) & 1u);   // round-to-nearest-even
    return (ushort)(u >> 16);
}
__device__ __forceinline__ float bf2f(ushort h) {
    return __builtin_bit_cast(float, (unsigned)h << 16);
}
__device__ __forceinline__ void split_bf(float f, ushort& h, ushort& l) {
    h = f2bf(f);
    l = f2bf(f - bf2f(h));
}

// ---- cast + transpose W into hi/lo bf16: Wt[n][k] = split(W[k][n]) ----
__global__ __launch_bounds__(256) void transpose_w_kernel(const float* __restrict__ w,
                                                          ushort* __restrict__ wth,
                                                          ushort* __restrict__ wtl) {
    int idx = blockIdx.x * 256 + threadIdx.x;
    int k = idx >> 9, n = idx & 511;
    ushort h, l;
    split_bf(w[idx], h, l);
    wth[n * Idim + k] = h;
    wtl[n * Idim + k] = l;
}

// ---- phase 1: pre = x @ W + bias via bf16x3 MFMA ----
#define BM 128
#define BN 128
#define BK 32
__global__ __launch_bounds__(256) void gemm_xw(
    const float* __restrict__ A,
    const ushort* __restrict__ Bth,
    const ushort* __restrict__ Btl,
    const float* __restrict__ bias,
    float* __restrict__ C,
    int M, int N, int K)
{
    __shared__ ushort AsH[BM][BK];
    __shared__ ushort AsL[BM][BK];
    __shared__ ushort BsH[BN][BK];
    __shared__ ushort BsL[BN][BK];
    int bm = blockIdx.x, bn = blockIdx.y;
    int tid = threadIdx.x;
    int wave = tid >> 6, lane = tid & 63;
    int wr = wave >> 1, wc = wave & 1;
    f32x4 acc[4][4] = {};
    const int row0 = bm * BM, col0 = bn * BN;
    const int sr = tid >> 1;
    const int sc = (tid & 1) * 16;

    for (int kt = 0; kt < K; kt += BK) {
        const float* gA = A + (size_t)(row0 + sr) * K + kt + sc;
        #pragma unroll
        for (int q = 0; q < 4; ++q) {
            float4 v = *(const float4*)(gA + q * 4);
            ushort4 h4, l4;
            split_bf(v.x, h4.x, l4.x);
            split_bf(v.y, h4.y, l4.y);
            split_bf(v.z, h4.z, l4.z);
            split_bf(v.w, h4.w, l4.w);
            *(ushort4*)&AsH[sr][sc + q * 4] = h4;
            *(ushort4*)&AsL[sr][sc + q * 4] = l4;
        }
        const int4* gBh = (const int4*)(Bth + (size_t)(col0 + sr) * K + kt + sc);
        *(int4*)&BsH[sr][sc]     = gBh[0];
        *(int4*)&BsH[sr][sc + 8] = gBh[1];
        const int4* gBl = (const int4*)(Btl + (size_t)(col0 + sr) * K + kt + sc);
        *(int4*)&BsL[sr][sc]     = gBl[0];
        *(int4*)&BsL[sr][sc + 8] = gBl[1];
        __syncthreads();

        const int r = lane & 15, kg = lane >> 4;
        bf16x8 ah[4], al[4], bh[4], bl[4];
        #pragma unroll
        for (int m = 0; m < 4; ++m) {
            ah[m] = *(const bf16x8*)&AsH[wr * 64 + m * 16 + r][kg * 8];
            al[m] = *(const bf16x8*)&AsL[wr * 64 + m * 16 + r][kg * 8];
        }
        #pragma unroll
        for (int n = 0; n < 4; ++n) {
            bh[n] = *(const bf16x8*)&BsH[wc * 64 + n * 16 + r][kg * 8];
            bl[n] = *(const bf16x8*)&BsL[wc * 64 + n * 16 + r][kg * 8];
        }
        #pragma unroll
        for (int m = 0; m < 4; ++m)
            #pragma unroll
            for (int n = 0; n < 4; ++n) {
                acc[m][n] = __builtin_amdgcn_mfma_f32_16x16x32_bf16(ah[m], bh[n], acc[m][n], 0, 0, 0);
                acc[m][n] = __builtin_amdgcn_mfma_f32_16x16x32_bf16(ah[m], bl[n], acc[m][n], 0, 0, 0);
                acc[m][n] = __builtin_amdgcn_mfma_f32_16x16x32_bf16(al[m], bh[n], acc[m][n], 0, 0, 0);
            }
        __syncthreads();
    }

    const int cl = lane & 15, rg = lane >> 4;
    #pragma unroll
    for (int n = 0; n < 4; ++n) {
        int gc = col0 + wc * 64 + n * 16 + cl;
        float bv = bias[gc];
        #pragma unroll
        for (int m = 0; m < 4; ++m) {
            int gr = row0 + wr * 64 + m * 16 + rg * 4;
            #pragma unroll
            for (int r2 = 0; r2 < 4; ++r2)
                C[(size_t)(gr + r2) * N + gc] = acc[m][n][r2] + bv;
        }
    }
}

// ---- phase 2: recurrence, column-split with R slice in LDS ----
__global__ __launch_bounds__(256) void rnn_sync_kernel(
    const float* __restrict__ Rw,    // [H][H] f32
    float* __restrict__ out,         // [B][T][H]: pre -> h in place
    float* __restrict__ hlast,       // [B][H]
    const float* __restrict__ h0,    // [B][H]
    int* __restrict__ flags)         // [32*8] version counters, zeroed per launch
{
    __shared__ float Rlds[Hdim * CPW];       // [col][k] f32, XOR-swizzled (128 KiB)
    __shared__ float hbuf[2][Hdim];          // h_{t-1} for both rows (4 KiB)
    __shared__ float part[CPW * 2 * 4];      // [col][row][kq] partials (2 KiB)

    const int w  = blockIdx.x;      // 0..255
    const int x  = w & 7;           // assumed XCD
    const int q  = w >> 3;          // 0..31
    const int j  = q & 7;           // member -> column slice
    const int gq = q >> 3;          // 0..3
    const int g  = x + 8 * gq;      // group id = b-pair, 0..31
    const size_t r0 = 2 * g, r1 = 2 * g + 1;
    const int col0 = j * CPW;
    const int tid = threadIdx.x;

    // ---- load R[:, col0..col0+63] into LDS, transposed + swizzled ----
    {
        const int c  = tid & 63;
        const int kb = tid >> 6;               // 0..3
        for (int kk = 0; kk < Hdim; kk += 4) {
            int k = kk + kb;
            float v = Rw[(size_t)k * Hdim + col0 + c];
            Rlds[c * 512 + (((k >> 2) ^ (c & 7)) << 2) + (k & 3)] = v;
        }
    }
    // ---- h_{-1} = h0 ----
    {
        int row = tid >> 7, off = (tid & 127) * 4;
        *(f32x4*)&hbuf[row][off] =
            *(const f32x4*)&h0[(row ? r1 : r0) * Hdim + off];
    }
    __syncthreads();

    const int c  = tid & 63;
    const int kq = tid >> 6;                   // 0..3, k-quarter
    const int cb = c * 512;
    const int cx = (c & 7) << 2;
    const int myflag = g * 8 + j;

    for (int t = 0; t < Tdim; ++t) {
        // prefetch pre-activation for this step (own slice, still holds pre)
        float pre = 0.f;
        if (tid < 128) {
            int pc = tid & 63, prow = tid >> 6;
            pre = out[((prow ? r1 : r0) * Tdim + t) * Hdim + col0 + pc];
        }

        // partial dot products: 2 rows x 1 col over this thread's 128 k's
        float a0 = 0.f, a1 = 0.f;
        #pragma unroll
        for (int i = 0; i < 32; ++i) {
            int k = kq * 128 + i * 4;
            f32x4 rv  = *(const f32x4*)&Rlds[cb + (k ^ cx)];
            f32x4 hv0 = *(const f32x4*)&hbuf[0][k];
            f32x4 hv1 = *(const f32x4*)&hbuf[1][k];
            a0 += rv.x * hv0.x + rv.y * hv0.y + rv.z * hv0.z + rv.w * hv0.w;
            a1 += rv.x * hv1.x + rv.y * hv1.y + rv.z * hv1.z + rv.w * hv1.w;
        }
        part[c * 8 + 0 + kq] = a0;
        part[c * 8 + 4 + kq] = a1;
        __syncthreads();

        if (tid < 128) {
            int pc = tid & 63, prow = tid >> 6;
            f32x4 p = *(const f32x4*)&part[pc * 8 + prow * 4];
            float gg = p.x + p.y + p.z + p.w + pre;
            gg = fminf(fmaxf(gg, -CLIPV), CLIPV);
            float hv = tanhf(gg);
            out[((prow ? r1 : r0) * Tdim + t) * Hdim + col0 + pc] = hv;
        }
        __threadfence();            // agent-scope fence before flag release
        __syncthreads();
        if (tid == 0)
            __hip_atomic_store(&flags[myflag], t + 1, __ATOMIC_RELEASE,
                               __HIP_MEMORY_SCOPE_AGENT);
        if (tid < 8) {
            while (__hip_atomic_load(&flags[g * 8 + tid], __ATOMIC_ACQUIRE,
                                     __HIP_MEMORY_SCOPE_AGENT) < t + 1) {}
        }
        __syncthreads();
        // reload full h_t (all 8 slices) from out
        {
            int row = tid >> 7, off = (tid & 127) * 4;
            *(f32x4*)&hbuf[row][off] =
                *(const f32x4*)&out[((row ? r1 : r0) * Tdim + t) * Hdim + off];
        }
        __syncthreads();
    }

    // h_last = h[T-1] (in hbuf after final reload)
    {
        int row = tid >> 7, off = (tid & 127) * 4;
        *(f32x4*)&hlast[(row ? r1 : r0) * Hdim + off] = *(const f32x4*)&hbuf[row][off];
    }
}

extern "C" void kernel_launch(void* const* d_in, const int* in_sizes, int n_in,
                              void* d_out, int out_size, void* d_ws, size_t ws_size,
                              hipStream_t stream) {
    const float* x    = (const float*)d_in[0];
    const float* W    = (const float*)d_in[1];
    const float* R    = (const float*)d_in[2];
    const float* bias = (const float*)d_in[3];
    const float* h0   = (const float*)d_in[4];
    float* out = (float*)d_out;

    ushort* wth = (ushort*)d_ws;                              // 512 KB
    ushort* wtl = wth + (size_t)Idim * Hdim;                  // 512 KB
    int* flags  = (int*)((char*)d_ws + (2u << 20));           // 1 KB at +2MB

    hipMemsetAsync(flags, 0, 32 * 8 * sizeof(int), stream);

    transpose_w_kernel<<<(Idim * Hdim + 255) / 256, 256, 0, stream>>>(W, wth, wtl);

    dim3 gg(Bdim * Tdim / BM, Hdim / BN);
    gemm_xw<<<gg, 256, 0, stream>>>(x, wth, wtl, bias, out, Bdim * Tdim, Hdim, Idim);

    rnn_sync_kernel<<<256, 256, 0, stream>>>(
        R, out, out + (size_t)Bdim * Tdim * Hdim, h0, flags);
}

// Round 4
// 1613.303 us; speedup vs baseline: 6.5428x; 6.5428x over previous
//
#include <hip/hip_runtime.h>

#define Bdim 64
#define Tdim 512
#define Idim 512
#define Hdim 512
#define CLIPV 10.0f

typedef __attribute__((ext_vector_type(4))) float f32x4;
typedef __attribute__((ext_vector_type(8))) short bf16x8;
typedef _Float16 half2v __attribute__((ext_vector_type(2)));

__device__ __forceinline__ ushort f2bf(float f) {
    unsigned u = __builtin_bit_cast(unsigned, f);
    u += 0x7fffu + ((u >> 16) & 1u);   // round-to-nearest-even
    return (ushort)(u >> 16);
}
__device__ __forceinline__ float bf2f(ushort h) {
    return __builtin_bit_cast(float, (unsigned)h << 16);
}
__device__ __forceinline__ void split_bf(float f, ushort& h, ushort& l) {
    h = f2bf(f);
    l = f2bf(f - bf2f(h));
}
__device__ __forceinline__ float dot2acc(uint r, uint h2, float acc) {
#if __has_builtin(__builtin_amdgcn_fdot2)
    return __builtin_amdgcn_fdot2(__builtin_bit_cast(half2v, r),
                                  __builtin_bit_cast(half2v, h2), acc, false);
#else
    half2v a = __builtin_bit_cast(half2v, r);
    half2v b = __builtin_bit_cast(half2v, h2);
    return acc + (float)a.x * (float)b.x + (float)a.y * (float)b.y;
#endif
}
__device__ __forceinline__ uint vcomp(uint4 v, int i) {
    return i == 0 ? v.x : i == 1 ? v.y : i == 2 ? v.z : v.w;
}
__device__ __forceinline__ uint packf16(float a, float b) {
    _Float16 fa = (_Float16)a, fb = (_Float16)b;
    return (uint)__builtin_bit_cast(ushort, fa) |
           ((uint)__builtin_bit_cast(ushort, fb) << 16);
}

// ---- cast + transpose W into hi/lo bf16 (for the feed-forward GEMM) ----
__global__ __launch_bounds__(256) void transpose_w_kernel(const float* __restrict__ w,
                                                          ushort* __restrict__ wth,
                                                          ushort* __restrict__ wtl) {
    int idx = blockIdx.x * 256 + threadIdx.x;
    int k = idx >> 9, n = idx & 511;
    ushort h, l;
    split_bf(w[idx], h, l);
    wth[n * Idim + k] = h;
    wtl[n * Idim + k] = l;
}

// ---- pack R into fp16 pair layout for the recurrence kernel ----
// layout: buf ∈ {0:reg half (k-off 0..63), 1:stream half (k-off 64..127)}
// dword index within buf: ((w*32 + i)*64 + l)*4 + q  (w=wave, i=k-pair, l=lane, q=col)
__global__ __launch_bounds__(256) void pack_r_kernel(const float* __restrict__ Rw,
                                                     uint* __restrict__ rpk) {
    int d = blockIdx.x * 256 + threadIdx.x;      // 0..131071
    int buf = d >> 16;
    int r = d & 65535;
    int q = r & 3, l = (r >> 2) & 63, i = (r >> 8) & 31, w = r >> 13;
    int t = w * 64 + l;
    int c = ((t & 127) << 2) + q;
    int kq = t >> 7;
    int k = kq * 128 + buf * 64 + 2 * i;
    rpk[d] = packf16(Rw[(size_t)k * Hdim + c], Rw[(size_t)(k + 1) * Hdim + c]);
}

// ---- phase 1: pre = x @ W + bias via bf16x3 MFMA ----
#define BM 128
#define BN 128
#define BK 32
__global__ __launch_bounds__(256) void gemm_xw(
    const float* __restrict__ A,
    const ushort* __restrict__ Bth,
    const ushort* __restrict__ Btl,
    const float* __restrict__ bias,
    float* __restrict__ C,
    int M, int N, int K)
{
    __shared__ ushort AsH[BM][BK];
    __shared__ ushort AsL[BM][BK];
    __shared__ ushort BsH[BN][BK];
    __shared__ ushort BsL[BN][BK];
    int bm = blockIdx.x, bn = blockIdx.y;
    int tid = threadIdx.x;
    int wave = tid >> 6, lane = tid & 63;
    int wr = wave >> 1, wc = wave & 1;
    f32x4 acc[4][4] = {};
    const int row0 = bm * BM, col0 = bn * BN;
    const int sr = tid >> 1;
    const int sc = (tid & 1) * 16;

    for (int kt = 0; kt < K; kt += BK) {
        const float* gA = A + (size_t)(row0 + sr) * K + kt + sc;
        #pragma unroll
        for (int q = 0; q < 4; ++q) {
            float4 v = *(const float4*)(gA + q * 4);
            ushort4 h4, l4;
            split_bf(v.x, h4.x, l4.x);
            split_bf(v.y, h4.y, l4.y);
            split_bf(v.z, h4.z, l4.z);
            split_bf(v.w, h4.w, l4.w);
            *(ushort4*)&AsH[sr][sc + q * 4] = h4;
            *(ushort4*)&AsL[sr][sc + q * 4] = l4;
        }
        const int4* gBh = (const int4*)(Bth + (size_t)(col0 + sr) * K + kt + sc);
        *(int4*)&BsH[sr][sc]     = gBh[0];
        *(int4*)&BsH[sr][sc + 8] = gBh[1];
        const int4* gBl = (const int4*)(Btl + (size_t)(col0 + sr) * K + kt + sc);
        *(int4*)&BsL[sr][sc]     = gBl[0];
        *(int4*)&BsL[sr][sc + 8] = gBl[1];
        __syncthreads();

        const int r = lane & 15, kg = lane >> 4;
        bf16x8 ah[4], al[4], bh[4], bl[4];
        #pragma unroll
        for (int m = 0; m < 4; ++m) {
            ah[m] = *(const bf16x8*)&AsH[wr * 64 + m * 16 + r][kg * 8];
            al[m] = *(const bf16x8*)&AsL[wr * 64 + m * 16 + r][kg * 8];
        }
        #pragma unroll
        for (int n = 0; n < 4; ++n) {
            bh[n] = *(const bf16x8*)&BsH[wc * 64 + n * 16 + r][kg * 8];
            bl[n] = *(const bf16x8*)&BsL[wc * 64 + n * 16 + r][kg * 8];
        }
        #pragma unroll
        for (int m = 0; m < 4; ++m)
            #pragma unroll
            for (int n = 0; n < 4; ++n) {
                acc[m][n] = __builtin_amdgcn_mfma_f32_16x16x32_bf16(ah[m], bh[n], acc[m][n], 0, 0, 0);
                acc[m][n] = __builtin_amdgcn_mfma_f32_16x16x32_bf16(ah[m], bl[n], acc[m][n], 0, 0, 0);
                acc[m][n] = __builtin_amdgcn_mfma_f32_16x16x32_bf16(al[m], bh[n], acc[m][n], 0, 0, 0);
            }
        __syncthreads();
    }

    const int cl = lane & 15, rg = lane >> 4;
    #pragma unroll
    for (int n = 0; n < 4; ++n) {
        int gc = col0 + wc * 64 + n * 16 + cl;
        float bv = bias[gc];
        #pragma unroll
        for (int m = 0; m < 4; ++m) {
            int gr = row0 + wr * 64 + m * 16 + rg * 4;
            #pragma unroll
            for (int r2 = 0; r2 < 4; ++r2)
                C[(size_t)(gr + r2) * N + gc] = acc[m][n][r2] + bv;
        }
    }
}

// ---- phase 2: recurrence. 64 WGs (1 batch row each), 512 threads, NO cross-WG sync.
// Half of R (fp16) lives in VGPRs (128/thread), the other half streams from L2 each step.
__global__ __launch_bounds__(512, 2) void rnn_reg_kernel(
    const uint* __restrict__ Rreg,   // [65536] packed fp16 pairs
    const uint* __restrict__ Rstr,   // [65536]
    float* __restrict__ out,         // [B][T][H]: pre -> h in place
    float* __restrict__ hlast,       // [B][H]
    const float* __restrict__ h0)    // [B][H]
{
    __shared__ uint h2[Hdim / 2];       // fp16 pairs of h_{t-1}, 1 KB
    __shared__ float part[4][Hdim];     // k-quarter partials, 8 KB

    const int row = blockIdx.x;
    const int tid = threadIdx.x;
    const int kq  = tid >> 7;           // k-quarter 0..3
    const int c0  = (tid & 127) * 4;    // 4 output columns
    const int w   = tid >> 6, l = tid & 63;

    // load register-resident half of R: 32 x uint4 = 128 dwords
    uint4 rr4[32];
    const uint* rbase = Rreg + w * 8192 + l * 4;
    #pragma unroll
    for (int i = 0; i < 32; ++i)
        rr4[i] = *(const uint4*)(rbase + i * 256);
    const uint* sbase = Rstr + w * 8192 + l * 4;

    if (tid < 256)
        h2[tid] = packf16(h0[row * Hdim + tid * 2], h0[row * Hdim + tid * 2 + 1]);
    __syncthreads();

    float* orow = out + (size_t)row * Tdim * Hdim;

    for (int t = 0; t < Tdim; ++t, orow += Hdim) {
        f32x4 pre = {};
        if (tid < 128) pre = *(const f32x4*)(orow + c0);

        float a0 = 0.f, a1 = 0.f, a2 = 0.f, a3 = 0.f;
        #pragma unroll
        for (int p = 0; p < 4; ++p) {
            // issue stream loads for this phase (8 x dwordx4)
            uint4 s4[8];
            #pragma unroll
            for (int i = 0; i < 8; ++i)
                s4[i] = *(const uint4*)(sbase + (p * 8 + i) * 256);
            // h fragments for this phase (broadcast LDS reads, wave-uniform addr)
            uint4 hr0 = *(const uint4*)&h2[kq * 64 + p * 8];
            uint4 hr1 = *(const uint4*)&h2[kq * 64 + p * 8 + 4];
            uint4 hs0 = *(const uint4*)&h2[kq * 64 + 32 + p * 8];
            uint4 hs1 = *(const uint4*)&h2[kq * 64 + 32 + p * 8 + 4];
            // register-half dot2s (also hides stream-load latency)
            #pragma unroll
            for (int i = 0; i < 8; ++i) {
                uint hv = (i < 4) ? vcomp(hr0, i) : vcomp(hr1, i - 4);
                uint4 rv = rr4[p * 8 + i];
                a0 = dot2acc(rv.x, hv, a0);
                a1 = dot2acc(rv.y, hv, a1);
                a2 = dot2acc(rv.z, hv, a2);
                a3 = dot2acc(rv.w, hv, a3);
            }
            // stream-half dot2s
            #pragma unroll
            for (int i = 0; i < 8; ++i) {
                uint hv = (i < 4) ? vcomp(hs0, i) : vcomp(hs1, i - 4);
                uint4 sv = s4[i];
                a0 = dot2acc(sv.x, hv, a0);
                a1 = dot2acc(sv.y, hv, a1);
                a2 = dot2acc(sv.z, hv, a2);
                a3 = dot2acc(sv.w, hv, a3);
            }
        }
        part[kq][c0 + 0] = a0;
        part[kq][c0 + 1] = a1;
        part[kq][c0 + 2] = a2;
        part[kq][c0 + 3] = a3;
        __syncthreads();

        if (tid < 128) {
            f32x4 p0 = *(const f32x4*)&part[0][c0];
            f32x4 p1 = *(const f32x4*)&part[1][c0];
            f32x4 p2 = *(const f32x4*)&part[2][c0];
            f32x4 p3 = *(const f32x4*)&part[3][c0];
            float g0 = p0[0] + p1[0] + p2[0] + p3[0] + pre[0];
            float g1 = p0[1] + p1[1] + p2[1] + p3[1] + pre[1];
            float g2 = p0[2] + p1[2] + p2[2] + p3[2] + pre[2];
            float g3 = p0[3] + p1[3] + p2[3] + p3[3] + pre[3];
            g0 = fminf(fmaxf(g0, -CLIPV), CLIPV);
            g1 = fminf(fmaxf(g1, -CLIPV), CLIPV);
            g2 = fminf(fmaxf(g2, -CLIPV), CLIPV);
            g3 = fminf(fmaxf(g3, -CLIPV), CLIPV);
            float v0 = tanhf(g0), v1 = tanhf(g1), v2 = tanhf(g2), v3 = tanhf(g3);
            f32x4 hv = {v0, v1, v2, v3};
            *(f32x4*)(orow + c0) = hv;
            h2[(c0 >> 1) + 0] = packf16(v0, v1);
            h2[(c0 >> 1) + 1] = packf16(v2, v3);
            if (t == Tdim - 1)
                *(f32x4*)&hlast[row * Hdim + c0] = hv;
        }
        __syncthreads();
    }
}

extern "C" void kernel_launch(void* const* d_in, const int* in_sizes, int n_in,
                              void* d_out, int out_size, void* d_ws, size_t ws_size,
                              hipStream_t stream) {
    const float* x    = (const float*)d_in[0];
    const float* W    = (const float*)d_in[1];
    const float* R    = (const float*)d_in[2];
    const float* bias = (const float*)d_in[3];
    const float* h0   = (const float*)d_in[4];
    float* out = (float*)d_out;

    ushort* wth = (ushort*)d_ws;                                // 512 KB
    ushort* wtl = wth + (size_t)Idim * Hdim;                    // 512 KB
    uint* rpk   = (uint*)((char*)d_ws + (1u << 20));            // 512 KB (reg+stream)
    uint* rreg  = rpk;
    uint* rstr  = rpk + 65536;

    transpose_w_kernel<<<(Idim * Hdim + 255) / 256, 256, 0, stream>>>(W, wth, wtl);
    pack_r_kernel<<<512, 256, 0, stream>>>(R, rpk);

    dim3 gg(Bdim * Tdim / BM, Hdim / BN);
    gemm_xw<<<gg, 256, 0, stream>>>(x, wth, wtl, bias, out, Bdim * Tdim, Hdim, Idim);

    rnn_reg_kernel<<<Bdim, 512, 0, stream>>>(
        rreg, rstr, out, out + (size_t)Bdim * Tdim * Hdim, h0);
}

// Round 5
// 960.938 us; speedup vs baseline: 10.9847x; 1.6789x over previous
//
#include <hip/hip_runtime.h>

#define Bdim 64
#define Tdim 512
#define Idim 512
#define Hdim 512
#define CLIPV 10.0f
#define NREGP 48        // k-pairs per thread in VGPRs
#define NLDSP 16        // k-pairs per thread in LDS (128 KB)

typedef __attribute__((ext_vector_type(4))) float f32x4;
typedef __attribute__((ext_vector_type(8))) short bf16x8;
typedef _Float16 half2v __attribute__((ext_vector_type(2)));

__device__ __forceinline__ ushort f2bf(float f) {
    unsigned u = __builtin_bit_cast(unsigned, f);
    u += 0x7fffu + ((u >> 16) & 1u);   // round-to-nearest-even
    return (ushort)(u >> 16);
}
__device__ __forceinline__ float bf2f(ushort h) {
    return __builtin_bit_cast(float, (unsigned)h << 16);
}
__device__ __forceinline__ void split_bf(float f, ushort& h, ushort& l) {
    h = f2bf(f);
    l = f2bf(f - bf2f(h));
}
__device__ __forceinline__ float dot2acc(uint r, uint h2, float acc) {
#if __has_builtin(__builtin_amdgcn_fdot2)
    return __builtin_amdgcn_fdot2(__builtin_bit_cast(half2v, r),
                                  __builtin_bit_cast(half2v, h2), acc, false);
#else
    half2v a = __builtin_bit_cast(half2v, r);
    half2v b = __builtin_bit_cast(half2v, h2);
    return acc + (float)a.x * (float)b.x + (float)a.y * (float)b.y;
#endif
}
__device__ __forceinline__ uint vcomp(uint4 v, int i) {
    return i == 0 ? v.x : i == 1 ? v.y : i == 2 ? v.z : v.w;
}
__device__ __forceinline__ uint packf16(float a, float b) {
    _Float16 fa = (_Float16)a, fb = (_Float16)b;
    return (uint)__builtin_bit_cast(ushort, fa) |
           ((uint)__builtin_bit_cast(ushort, fb) << 16);
}

// ---- cast + transpose W into hi/lo bf16 (feed-forward GEMM operands) ----
__global__ __launch_bounds__(256) void transpose_w_kernel(const float* __restrict__ w,
                                                          ushort* __restrict__ wth,
                                                          ushort* __restrict__ wtl) {
    int idx = blockIdx.x * 256 + threadIdx.x;
    int k = idx >> 9, n = idx & 511;
    ushort h, l;
    split_bf(w[idx], h, l);
    wth[n * Idim + k] = h;
    wtl[n * Idim + k] = l;
}

// ---- pack R into fp16 pairs, layout d = i*2048 + t*4 + q ----
// thread t covers k-quarter (t>>7) and cols (t&127)*4+q; pair i -> k = kq*128+2i
__global__ __launch_bounds__(256) void pack_r_kernel(const float* __restrict__ Rw,
                                                     uint* __restrict__ rpk) {
    int d = blockIdx.x * 256 + threadIdx.x;      // 0..131071
    int i = d >> 11;
    int rem = d & 2047;
    int t = rem >> 2, q = rem & 3;
    int k = (t >> 7) * 128 + 2 * i;
    int c = ((t & 127) << 2) + q;
    rpk[d] = packf16(Rw[(size_t)k * Hdim + c], Rw[(size_t)(k + 1) * Hdim + c]);
}

// ---- phase 1: pre = x @ W + bias via bf16x3 MFMA ----
#define BM 128
#define BN 128
#define BK 32
__global__ __launch_bounds__(256) void gemm_xw(
    const float* __restrict__ A,
    const ushort* __restrict__ Bth,
    const ushort* __restrict__ Btl,
    const float* __restrict__ bias,
    float* __restrict__ C,
    int M, int N, int K)
{
    __shared__ ushort AsH[BM][BK];
    __shared__ ushort AsL[BM][BK];
    __shared__ ushort BsH[BN][BK];
    __shared__ ushort BsL[BN][BK];
    int bm = blockIdx.x, bn = blockIdx.y;
    int tid = threadIdx.x;
    int wave = tid >> 6, lane = tid & 63;
    int wr = wave >> 1, wc = wave & 1;
    f32x4 acc[4][4] = {};
    const int row0 = bm * BM, col0 = bn * BN;
    const int sr = tid >> 1;
    const int sc = (tid & 1) * 16;

    for (int kt = 0; kt < K; kt += BK) {
        const float* gA = A + (size_t)(row0 + sr) * K + kt + sc;
        #pragma unroll
        for (int q = 0; q < 4; ++q) {
            float4 v = *(const float4*)(gA + q * 4);
            ushort4 h4, l4;
            split_bf(v.x, h4.x, l4.x);
            split_bf(v.y, h4.y, l4.y);
            split_bf(v.z, h4.z, l4.z);
            split_bf(v.w, h4.w, l4.w);
            *(ushort4*)&AsH[sr][sc + q * 4] = h4;
            *(ushort4*)&AsL[sr][sc + q * 4] = l4;
        }
        const int4* gBh = (const int4*)(Bth + (size_t)(col0 + sr) * K + kt + sc);
        *(int4*)&BsH[sr][sc]     = gBh[0];
        *(int4*)&BsH[sr][sc + 8] = gBh[1];
        const int4* gBl = (const int4*)(Btl + (size_t)(col0 + sr) * K + kt + sc);
        *(int4*)&BsL[sr][sc]     = gBl[0];
        *(int4*)&BsL[sr][sc + 8] = gBl[1];
        __syncthreads();

        const int r = lane & 15, kg = lane >> 4;
        bf16x8 ah[4], al[4], bh[4], bl[4];
        #pragma unroll
        for (int m = 0; m < 4; ++m) {
            ah[m] = *(const bf16x8*)&AsH[wr * 64 + m * 16 + r][kg * 8];
            al[m] = *(const bf16x8*)&AsL[wr * 64 + m * 16 + r][kg * 8];
        }
        #pragma unroll
        for (int n = 0; n < 4; ++n) {
            bh[n] = *(const bf16x8*)&BsH[wc * 64 + n * 16 + r][kg * 8];
            bl[n] = *(const bf16x8*)&BsL[wc * 64 + n * 16 + r][kg * 8];
        }
        #pragma unroll
        for (int m = 0; m < 4; ++m)
            #pragma unroll
            for (int n = 0; n < 4; ++n) {
                acc[m][n] = __builtin_amdgcn_mfma_f32_16x16x32_bf16(ah[m], bh[n], acc[m][n], 0, 0, 0);
                acc[m][n] = __builtin_amdgcn_mfma_f32_16x16x32_bf16(ah[m], bl[n], acc[m][n], 0, 0, 0);
                acc[m][n] = __builtin_amdgcn_mfma_f32_16x16x32_bf16(al[m], bh[n], acc[m][n], 0, 0, 0);
            }
        __syncthreads();
    }

    const int cl = lane & 15, rg = lane >> 4;
    #pragma unroll
    for (int n = 0; n < 4; ++n) {
        int gc = col0 + wc * 64 + n * 16 + cl;
        float bv = bias[gc];
        #pragma unroll
        for (int m = 0; m < 4; ++m) {
            int gr = row0 + wr * 64 + m * 16 + rg * 4;
            #pragma unroll
            for (int r2 = 0; r2 < 4; ++r2)
                C[(size_t)(gr + r2) * N + gc] = acc[m][n][r2] + bv;
        }
    }
}

// ---- phase 2: recurrence. 64 WGs (1 row each), 512 threads, zero cross-WG sync.
// ALL of R (fp16) resident per CU: 192 dwords/thread in VGPRs + 128 KB in LDS.
__global__ __launch_bounds__(512, 2) void rnn_reg_kernel(
    const uint* __restrict__ Rpk,    // [131072] packed fp16 pairs
    float* __restrict__ out,         // [B][T][H]: pre -> h in place
    float* __restrict__ hlast,       // [B][H]
    const float* __restrict__ h0)    // [B][H]
{
    __shared__ uint Rlds[NLDSP * 2048];   // 128 KB
    __shared__ uint h2[Hdim / 2];         // 1 KB, fp16 pairs of h_{t-1}
    __shared__ float part[4][Hdim];       // 8 KB, k-quarter partials

    const int tid = threadIdx.x;
    const int row = blockIdx.x;
    const int kq  = tid >> 7;             // k-quarter (uniform per wave)
    const int c0  = (tid & 127) * 4;      // 4 output columns
    const int hb  = kq * 64;

    // load register-resident R: 48 x uint4 = 192 dwords
    uint4 rr4[NREGP];
    const uint* rbase = Rpk + tid * 4;
    #pragma unroll
    for (int i = 0; i < NREGP; ++i)
        rr4[i] = *(const uint4*)(rbase + i * 2048);
    // stage LDS-resident R: 16 x uint4 per thread, lane-consecutive layout
    #pragma unroll
    for (int ip = 0; ip < NLDSP; ++ip)
        *(uint4*)&Rlds[ip * 2048 + tid * 4] =
            *(const uint4*)(rbase + (NREGP + ip) * 2048);

    if (tid < 256)
        h2[tid] = packf16(h0[row * Hdim + 2 * tid], h0[row * Hdim + 2 * tid + 1]);
    __syncthreads();

    float* orow = out + (size_t)row * Tdim * Hdim;

    for (int t = 0; t < Tdim; ++t, orow += Hdim) {
        f32x4 pre = {};
        if (tid < 128) pre = *(const f32x4*)(orow + c0);   // prefetch pre-activation

        float a0 = 0.f, a1 = 0.f, a2 = 0.f, a3 = 0.f;
        // register part: pairs 0..47 (h reads are wave-uniform broadcasts)
        #pragma unroll
        for (int ch = 0; ch < 12; ++ch) {
            uint4 hh = *(const uint4*)&h2[hb + ch * 4];
            #pragma unroll
            for (int i = 0; i < 4; ++i) {
                uint hv = vcomp(hh, i);
                uint4 rv = rr4[ch * 4 + i];
                a0 = dot2acc(rv.x, hv, a0);
                a1 = dot2acc(rv.y, hv, a1);
                a2 = dot2acc(rv.z, hv, a2);
                a3 = dot2acc(rv.w, hv, a3);
            }
        }
        // LDS part: pairs 48..63, conflict-free ds_read_b128
        #pragma unroll
        for (int ch = 0; ch < 4; ++ch) {
            uint4 hh = *(const uint4*)&h2[hb + 48 + ch * 4];
            #pragma unroll
            for (int i = 0; i < 4; ++i) {
                uint hv = vcomp(hh, i);
                uint4 rv = *(const uint4*)&Rlds[(ch * 4 + i) * 2048 + tid * 4];
                a0 = dot2acc(rv.x, hv, a0);
                a1 = dot2acc(rv.y, hv, a1);
                a2 = dot2acc(rv.z, hv, a2);
                a3 = dot2acc(rv.w, hv, a3);
            }
        }
        part[kq][c0 + 0] = a0;
        part[kq][c0 + 1] = a1;
        part[kq][c0 + 2] = a2;
        part[kq][c0 + 3] = a3;
        __syncthreads();

        if (tid < 128) {
            f32x4 p0 = *(const f32x4*)&part[0][c0];
            f32x4 p1 = *(const f32x4*)&part[1][c0];
            f32x4 p2 = *(const f32x4*)&part[2][c0];
            f32x4 p3 = *(const f32x4*)&part[3][c0];
            float g0 = p0[0] + p1[0] + p2[0] + p3[0] + pre[0];
            float g1 = p0[1] + p1[1] + p2[1] + p3[1] + pre[1];
            float g2 = p0[2] + p1[2] + p2[2] + p3[2] + pre[2];
            float g3 = p0[3] + p1[3] + p2[3] + p3[3] + pre[3];
            g0 = fminf(fmaxf(g0, -CLIPV), CLIPV);
            g1 = fminf(fmaxf(g1, -CLIPV), CLIPV);
            g2 = fminf(fmaxf(g2, -CLIPV), CLIPV);
            g3 = fminf(fmaxf(g3, -CLIPV), CLIPV);
            float v0 = tanhf(g0), v1 = tanhf(g1), v2 = tanhf(g2), v3 = tanhf(g3);
            f32x4 hv = {v0, v1, v2, v3};
            *(f32x4*)(orow + c0) = hv;
            h2[(c0 >> 1) + 0] = packf16(v0, v1);
            h2[(c0 >> 1) + 1] = packf16(v2, v3);
            if (t == Tdim - 1)
                *(f32x4*)&hlast[row * Hdim + c0] = hv;
        }
        __syncthreads();
    }
}

extern "C" void kernel_launch(void* const* d_in, const int* in_sizes, int n_in,
                              void* d_out, int out_size, void* d_ws, size_t ws_size,
                              hipStream_t stream) {
    const float* x    = (const float*)d_in[0];
    const float* W    = (const float*)d_in[1];
    const float* R    = (const float*)d_in[2];
    const float* bias = (const float*)d_in[3];
    const float* h0   = (const float*)d_in[4];
    float* out = (float*)d_out;

    ushort* wth = (ushort*)d_ws;                                // 512 KB
    ushort* wtl = wth + (size_t)Idim * Hdim;                    // 512 KB
    uint* rpk   = (uint*)((char*)d_ws + (1u << 20));            // 512 KB

    transpose_w_kernel<<<(Idim * Hdim + 255) / 256, 256, 0, stream>>>(W, wth, wtl);
    pack_r_kernel<<<512, 256, 0, stream>>>(R, rpk);

    dim3 gg(Bdim * Tdim / BM, Hdim / BN);
    gemm_xw<<<gg, 256, 0, stream>>>(x, wth, wtl, bias, out, Bdim * Tdim, Hdim, Idim);

    rnn_reg_kernel<<<Bdim, 512, 0, stream>>>(
        rpk, out, out + (size_t)Bdim * Tdim * Hdim, h0);
}

// Round 6
// 815.261 us; speedup vs baseline: 12.9475x; 1.1787x over previous
//
#include <hip/hip_runtime.h>

#define Bdim 64
#define Tdim 512
#define Idim 512
#define Hdim 512
#define CLIPV 10.0f
#define NREGP 52        // k-pairs per thread in VGPRs/AGPRs
#define NLDSP 12        // k-pairs per thread in LDS (96 KB)

typedef __attribute__((ext_vector_type(4))) float f32x4;
typedef __attribute__((ext_vector_type(8))) short bf16x8;
typedef _Float16 half2v __attribute__((ext_vector_type(2)));

__device__ __forceinline__ ushort f2bf(float f) {
    unsigned u = __builtin_bit_cast(unsigned, f);
    u += 0x7fffu + ((u >> 16) & 1u);   // round-to-nearest-even
    return (ushort)(u >> 16);
}
__device__ __forceinline__ float bf2f(ushort h) {
    return __builtin_bit_cast(float, (unsigned)h << 16);
}
__device__ __forceinline__ void split_bf(float f, ushort& h, ushort& l) {
    h = f2bf(f);
    l = f2bf(f - bf2f(h));
}
__device__ __forceinline__ float dot2acc(uint r, uint h2, float acc) {
#if __has_builtin(__builtin_amdgcn_fdot2)
    return __builtin_amdgcn_fdot2(__builtin_bit_cast(half2v, r),
                                  __builtin_bit_cast(half2v, h2), acc, false);
#else
    half2v a = __builtin_bit_cast(half2v, r);
    half2v b = __builtin_bit_cast(half2v, h2);
    return acc + (float)a.x * (float)b.x + (float)a.y * (float)b.y;
#endif
}
__device__ __forceinline__ uint packf16(float a, float b) {
    _Float16 fa = (_Float16)a, fb = (_Float16)b;
    return (uint)__builtin_bit_cast(ushort, fa) |
           ((uint)__builtin_bit_cast(ushort, fb) << 16);
}
__device__ __forceinline__ ushort f2h(float f) {
    _Float16 h = (_Float16)f;
    return __builtin_bit_cast(ushort, h);
}
__device__ __forceinline__ float fastrcp(float x) {
#if __has_builtin(__builtin_amdgcn_rcpf)
    return __builtin_amdgcn_rcpf(x);
#else
    return 1.0f / x;
#endif
}

// ---- cast + transpose W into hi/lo bf16 (feed-forward GEMM operands) ----
__global__ __launch_bounds__(256) void transpose_w_kernel(const float* __restrict__ w,
                                                          ushort* __restrict__ wth,
                                                          ushort* __restrict__ wtl) {
    int idx = blockIdx.x * 256 + threadIdx.x;
    int k = idx >> 9, n = idx & 511;
    ushort h, l;
    split_bf(w[idx], h, l);
    wth[n * Idim + k] = h;
    wtl[n * Idim + k] = l;
}

// ---- pack R into fp16 pairs, layout d = i*2048 + t*4 + q ----
// thread t covers k-quarter (t>>7) and cols (t&127)*4+q; pair i -> k = kq*128+2i
__global__ __launch_bounds__(256) void pack_r_kernel(const float* __restrict__ Rw,
                                                     uint* __restrict__ rpk) {
    int d = blockIdx.x * 256 + threadIdx.x;      // 0..131071
    int i = d >> 11;
    int rem = d & 2047;
    int t = rem >> 2, q = rem & 3;
    int k = (t >> 7) * 128 + 2 * i;
    int c = ((t & 127) << 2) + q;
    rpk[d] = packf16(Rw[(size_t)k * Hdim + c], Rw[(size_t)(k + 1) * Hdim + c]);
}

// ---- phase 1: pre = x @ W + bias via bf16x3 MFMA ----
#define BM 128
#define BN 128
#define BK 32
__global__ __launch_bounds__(256) void gemm_xw(
    const float* __restrict__ A,
    const ushort* __restrict__ Bth,
    const ushort* __restrict__ Btl,
    const float* __restrict__ bias,
    float* __restrict__ C,
    int M, int N, int K)
{
    __shared__ ushort AsH[BM][BK];
    __shared__ ushort AsL[BM][BK];
    __shared__ ushort BsH[BN][BK];
    __shared__ ushort BsL[BN][BK];
    int bm = blockIdx.x, bn = blockIdx.y;
    int tid = threadIdx.x;
    int wave = tid >> 6, lane = tid & 63;
    int wr = wave >> 1, wc = wave & 1;
    f32x4 acc[4][4] = {};
    const int row0 = bm * BM, col0 = bn * BN;
    const int sr = tid >> 1;
    const int sc = (tid & 1) * 16;

    for (int kt = 0; kt < K; kt += BK) {
        const float* gA = A + (size_t)(row0 + sr) * K + kt + sc;
        #pragma unroll
        for (int q = 0; q < 4; ++q) {
            float4 v = *(const float4*)(gA + q * 4);
            ushort4 h4, l4;
            split_bf(v.x, h4.x, l4.x);
            split_bf(v.y, h4.y, l4.y);
            split_bf(v.z, h4.z, l4.z);
            split_bf(v.w, h4.w, l4.w);
            *(ushort4*)&AsH[sr][sc + q * 4] = h4;
            *(ushort4*)&AsL[sr][sc + q * 4] = l4;
        }
        const int4* gBh = (const int4*)(Bth + (size_t)(col0 + sr) * K + kt + sc);
        *(int4*)&BsH[sr][sc]     = gBh[0];
        *(int4*)&BsH[sr][sc + 8] = gBh[1];
        const int4* gBl = (const int4*)(Btl + (size_t)(col0 + sr) * K + kt + sc);
        *(int4*)&BsL[sr][sc]     = gBl[0];
        *(int4*)&BsL[sr][sc + 8] = gBl[1];
        __syncthreads();

        const int r = lane & 15, kg = lane >> 4;
        bf16x8 ah[4], al[4], bh[4], bl[4];
        #pragma unroll
        for (int m = 0; m < 4; ++m) {
            ah[m] = *(const bf16x8*)&AsH[wr * 64 + m * 16 + r][kg * 8];
            al[m] = *(const bf16x8*)&AsL[wr * 64 + m * 16 + r][kg * 8];
        }
        #pragma unroll
        for (int n = 0; n < 4; ++n) {
            bh[n] = *(const bf16x8*)&BsH[wc * 64 + n * 16 + r][kg * 8];
            bl[n] = *(const bf16x8*)&BsL[wc * 64 + n * 16 + r][kg * 8];
        }
        #pragma unroll
        for (int m = 0; m < 4; ++m)
            #pragma unroll
            for (int n = 0; n < 4; ++n) {
                acc[m][n] = __builtin_amdgcn_mfma_f32_16x16x32_bf16(ah[m], bh[n], acc[m][n], 0, 0, 0);
                acc[m][n] = __builtin_amdgcn_mfma_f32_16x16x32_bf16(ah[m], bl[n], acc[m][n], 0, 0, 0);
                acc[m][n] = __builtin_amdgcn_mfma_f32_16x16x32_bf16(al[m], bh[n], acc[m][n], 0, 0, 0);
            }
        __syncthreads();
    }

    const int cl = lane & 15, rg = lane >> 4;
    #pragma unroll
    for (int n = 0; n < 4; ++n) {
        int gc = col0 + wc * 64 + n * 16 + cl;
        float bv = bias[gc];
        #pragma unroll
        for (int m = 0; m < 4; ++m) {
            int gr = row0 + wr * 64 + m * 16 + rg * 4;
            #pragma unroll
            for (int r2 = 0; r2 < 4; ++r2)
                C[(size_t)(gr + r2) * N + gc] = acc[m][n][r2] + bv;
        }
    }
}

// ---- phase 2: recurrence. 64 WGs (1 row each), 512 threads, zero cross-WG sync.
// All of R (fp16) CU-resident: 208 dwords/thread in VGPR/AGPR + 96 KB in LDS.
// h broadcast via one b32 LDS read/lane + readlane into the dot2 SGPR operand.
__global__ __launch_bounds__(512, 2) void rnn_reg_kernel(
    const uint* __restrict__ Rpk,    // [131072] packed fp16 pairs
    float* __restrict__ out,         // [B][T][H]: pre -> h in place
    float* __restrict__ hlast,       // [B][H]
    const float* __restrict__ h0)    // [B][H]
{
    __shared__ uint Rlds[NLDSP * 2048];   // 96 KB
    __shared__ ushort h1[Hdim];           // 1 KB, fp16 h_{t-1}
    __shared__ float part[4][Hdim];       // 8 KB, k-quarter partials

    const int tid  = threadIdx.x;
    const int row  = blockIdx.x;
    const int kq   = tid >> 7;            // k-quarter (uniform per wave)
    const int lane = tid & 63;
    const int c0   = (tid & 127) * 4;     // 4 output columns (dot phase)
    const int hb   = kq * 64;             // uint-pair base of this wave's quarter

    // register-resident R: 52 x uint4 = 208 dwords
    uint4 rr4[NREGP];
    const uint* rbase = Rpk + tid * 4;
    #pragma unroll
    for (int i = 0; i < NREGP; ++i)
        rr4[i] = *(const uint4*)(rbase + i * 2048);
    // LDS-resident R: 12 x uint4 per thread, lane-consecutive layout
    #pragma unroll
    for (int ip = 0; ip < NLDSP; ++ip)
        *(uint4*)&Rlds[ip * 2048 + tid * 4] =
            *(const uint4*)(rbase + (NREGP + ip) * 2048);

    h1[tid] = f2h(h0[row * Hdim + tid]);
    __syncthreads();

    float* orow = out + (size_t)row * Tdim * Hdim;

    for (int t = 0; t < Tdim; ++t, orow += Hdim) {
        float pre = orow[tid];                        // issued early, used in finalize
        uint hval = ((const uint*)h1)[hb + lane];     // lane's h pair; 1 b32, conflict-free

        float a0 = 0.f, a1 = 0.f, a2 = 0.f, a3 = 0.f;
        // register part: pairs 0..NREGP-1, h via readlane broadcast (SGPR operand)
        #pragma unroll
        for (int i = 0; i < NREGP; ++i) {
            uint hvi = __builtin_amdgcn_readlane(hval, i);
            uint4 rv = rr4[i];
            a0 = dot2acc(rv.x, hvi, a0);
            a1 = dot2acc(rv.y, hvi, a1);
            a2 = dot2acc(rv.z, hvi, a2);
            a3 = dot2acc(rv.w, hvi, a3);
        }
        // LDS part: pairs NREGP..63
        #pragma unroll
        for (int i = 0; i < NLDSP; ++i) {
            uint hvi = __builtin_amdgcn_readlane(hval, NREGP + i);
            uint4 rv = *(const uint4*)&Rlds[i * 2048 + tid * 4];
            a0 = dot2acc(rv.x, hvi, a0);
            a1 = dot2acc(rv.y, hvi, a1);
            a2 = dot2acc(rv.z, hvi, a2);
            a3 = dot2acc(rv.w, hvi, a3);
        }
        *(f32x4*)&part[kq][c0] = (f32x4){a0, a1, a2, a3};
        __syncthreads();

        // finalize: all 512 threads, one column each
        float s = part[0][tid] + part[1][tid] + part[2][tid] + part[3][tid] + pre;
        s = fminf(fmaxf(s, -CLIPV), CLIPV);
        float e = __expf(2.0f * s);                   // v_exp_f32
        float v = (e - 1.0f) * fastrcp(e + 1.0f);     // tanh(s)
        orow[tid] = v;
        h1[tid] = f2h(v);
        if (t == Tdim - 1) hlast[row * Hdim + tid] = v;
        __syncthreads();
    }
}

extern "C" void kernel_launch(void* const* d_in, const int* in_sizes, int n_in,
                              void* d_out, int out_size, void* d_ws, size_t ws_size,
                              hipStream_t stream) {
    const float* x    = (const float*)d_in[0];
    const float* W    = (const float*)d_in[1];
    const float* R    = (const float*)d_in[2];
    const float* bias = (const float*)d_in[3];
    const float* h0   = (const float*)d_in[4];
    float* out = (float*)d_out;

    ushort* wth = (ushort*)d_ws;                                // 512 KB
    ushort* wtl = wth + (size_t)Idim * Hdim;                    // 512 KB
    uint* rpk   = (uint*)((char*)d_ws + (1u << 20));            // 512 KB

    transpose_w_kernel<<<(Idim * Hdim + 255) / 256, 256, 0, stream>>>(W, wth, wtl);
    pack_r_kernel<<<512, 256, 0, stream>>>(R, rpk);

    dim3 gg(Bdim * Tdim / BM, Hdim / BN);
    gemm_xw<<<gg, 256, 0, stream>>>(x, wth, wtl, bias, out, Bdim * Tdim, Hdim, Idim);

    rnn_reg_kernel<<<Bdim, 512, 0, stream>>>(
        rpk, out, out + (size_t)Bdim * Tdim * Hdim, h0);
}